// Round 2
// baseline (228.473 us; speedup 1.0000x reference)
//
#include <hip/hip_runtime.h>

#define B_DIM   2048
#define IN_DIM  4096
#define OUT_DIM 4096
#define FAN     64

// R2 design: occupancy 2x over R1.
//  - block = 256 threads, 1 output neuron per thread; grid = 64 bsegs(32 rows) x 16 oblocks
//    = 1024 blocks -> 4 blocks/CU (4 x 32KB = 128KB LDS, <=160KB), 16 waves/CU.
//  - tile = 4 batch rows, packed bf16: cell c (8B) = col c of rows b0..b0+3
//    (dword0 = rows 0,1; dword1 = rows 2,3). Gather = ds_read_b64 -> 4 MACs.
//  - cell-PAIR swizzle: pair u=c>>1 stored at slot s(u)=u^((u>>3)&7), cell byte addr
//    = s(u)*16 + (c&1)*8. Staging writes whole pairs with ds_write_b128; for lane-
//    consecutive pairs the xor spreads writes over all 8 bank-groups (conflict-free).
//    Swizzle is folded into precomputed per-thread gather addresses.
//  - gather addrs < 32KB fit in 16 bits: packed 2/reg (32 VGPRs) + weights fp32 (64)
//    + acc (4) stays under 128 VGPRs -> 4 waves/SIMD with __launch_bounds__(256,4).

__device__ __forceinline__ unsigned bf16_rne(float f) {
    unsigned u = __float_as_uint(f);
    return (u + 0x7fffu + ((u >> 16) & 1u)) >> 16;   // round-to-nearest-even bf16
}

__device__ __forceinline__ unsigned swz(unsigned u) {
    return u ^ ((u >> 3) & 7u);                      // cell-pair slot swizzle
}

__device__ __forceinline__ unsigned gaddr(int c) {   // swizzled byte addr of cell c
    unsigned u = (unsigned)c >> 1;
    return (swz(u) << 4) + (((unsigned)c & 1u) << 3);
}

__global__ __launch_bounds__(256, 4) void condensed_kernel(
    const float* __restrict__ input,
    const float* __restrict__ weight,
    const float* __restrict__ bias,
    const int*   __restrict__ mask,
    float*       __restrict__ out)
{
    __shared__ __align__(16) unsigned lds[IN_DIM * 2];   // 32 KB = 2048 pairs x 16B

    const int tid  = threadIdx.x;
    const int o    = blockIdx.y * 256 + tid;
    const int bseg = blockIdx.x * 32;

    // ---- idx -> packed swizzled LDS byte addresses (2 per reg) + fp32 weights ----
    unsigned paddr[FAN / 2];
    float    wv[FAN];
    {
        const int4*   mv = reinterpret_cast<const int4*>(mask)     + o * (FAN / 4);
        const float4* wp = reinterpret_cast<const float4*>(weight) + o * (FAN / 4);
        #pragma unroll
        for (int j = 0; j < FAN / 4; ++j) {
            int4   m4 = mv[j];
            float4 w4 = wp[j];
            paddr[2*j+0] = gaddr(m4.x) | (gaddr(m4.y) << 16);
            paddr[2*j+1] = gaddr(m4.z) | (gaddr(m4.w) << 16);
            wv[4*j+0] = w4.x;
            wv[4*j+1] = w4.y;
            wv[4*j+2] = w4.z;
            wv[4*j+3] = w4.w;
        }
    }
    const float bv = bias[o];

    for (int bt = 0; bt < 8; ++bt) {                 // 8 tiles x 4 rows = 32 rows
        const int b0 = bseg + bt * 4;

        __syncthreads();                             // protect previous tile's readers

        // ---- stage 4 rows (fp32 -> bf16, whole 16B cell-pairs, b128 writes) ----
        #pragma unroll
        for (int it = 0; it < 4; ++it) {
            const int cb = (it * 256 + tid) * 4;     // 4 columns per item
            const float* p0 = input + (size_t)b0 * IN_DIM + cb;
            const float4 r0 = *reinterpret_cast<const float4*>(p0);
            const float4 r1 = *reinterpret_cast<const float4*>(p0 + IN_DIM);
            const float4 r2 = *reinterpret_cast<const float4*>(p0 + 2 * IN_DIM);
            const float4 r3 = *reinterpret_cast<const float4*>(p0 + 3 * IN_DIM);

            uint4 q0, q1;                            // pair u0 = cols cb,cb+1; u0+1 = cb+2,cb+3
            q0.x = bf16_rne(r0.x) | (bf16_rne(r1.x) << 16);
            q0.y = bf16_rne(r2.x) | (bf16_rne(r3.x) << 16);
            q0.z = bf16_rne(r0.y) | (bf16_rne(r1.y) << 16);
            q0.w = bf16_rne(r2.y) | (bf16_rne(r3.y) << 16);
            q1.x = bf16_rne(r0.z) | (bf16_rne(r1.z) << 16);
            q1.y = bf16_rne(r2.z) | (bf16_rne(r3.z) << 16);
            q1.z = bf16_rne(r0.w) | (bf16_rne(r1.w) << 16);
            q1.w = bf16_rne(r2.w) | (bf16_rne(r3.w) << 16);

            const unsigned u0 = (unsigned)cb >> 1;   // even
            *reinterpret_cast<uint4*>(reinterpret_cast<char*>(lds) + (swz(u0)     << 4)) = q0;
            *reinterpret_cast<uint4*>(reinterpret_cast<char*>(lds) + (swz(u0 + 1) << 4)) = q1;
        }

        __syncthreads();

        // ---- gather + accumulate: 64 x ds_read_b64, 4 rows each ----
        float acc0 = 0.f, acc1 = 0.f, acc2 = 0.f, acc3 = 0.f;
        #pragma unroll
        for (int jj = 0; jj < FAN / 2; ++jj) {
            const unsigned pa = paddr[jj];
            const uint2 g0 = *reinterpret_cast<const uint2*>(
                reinterpret_cast<const char*>(lds) + (pa & 0xffffu));
            const uint2 g1 = *reinterpret_cast<const uint2*>(
                reinterpret_cast<const char*>(lds) + (pa >> 16));
            const float w0 = wv[2*jj+0];
            const float w1 = wv[2*jj+1];
            acc0 = fmaf(__uint_as_float(g0.x << 16),          w0, acc0);
            acc1 = fmaf(__uint_as_float(g0.x & 0xffff0000u),  w0, acc1);
            acc2 = fmaf(__uint_as_float(g0.y << 16),          w0, acc2);
            acc3 = fmaf(__uint_as_float(g0.y & 0xffff0000u),  w0, acc3);
            acc0 = fmaf(__uint_as_float(g1.x << 16),          w1, acc0);
            acc1 = fmaf(__uint_as_float(g1.x & 0xffff0000u),  w1, acc1);
            acc2 = fmaf(__uint_as_float(g1.y << 16),          w1, acc2);
            acc3 = fmaf(__uint_as_float(g1.y & 0xffff0000u),  w1, acc3);
        }

        // ---- write 4 outputs (coalesced across threads) ----
        float* op = out + (size_t)b0 * OUT_DIM + o;
        op[0 * OUT_DIM] = acc0 + bv;
        op[1 * OUT_DIM] = acc1 + bv;
        op[2 * OUT_DIM] = acc2 + bv;
        op[3 * OUT_DIM] = acc3 + bv;
    }
}

extern "C" void kernel_launch(void* const* d_in, const int* in_sizes, int n_in,
                              void* d_out, int out_size, void* d_ws, size_t ws_size,
                              hipStream_t stream) {
    const float* input  = (const float*)d_in[0];
    const float* weight = (const float*)d_in[1];
    const float* bias   = (const float*)d_in[2];
    const int*   mask   = (const int*)d_in[3];
    float*       out    = (float*)d_out;

    dim3 grid(64, 16);   // 64 bsegs x 16 oblocks = 1024 blocks -> 4 blocks/CU
    condensed_kernel<<<grid, 256, 0, stream>>>(input, weight, bias, mask, out);
}

// Round 3
// 133.873 us; speedup vs baseline: 1.7066x; 1.7066x over previous
//
#include <hip/hip_runtime.h>

#define B_DIM   2048
#define IN_DIM  4096
#define OUT_DIM 4096
#define FAN     64

// R3: two-phase. Phase 1 packs input fp32 -> bf16 "cell" layout in d_ws ONCE
// (R1/R2 re-packed per oblock: 16x redundant VALU + fetch). Phase 2 restores the
// R1 grid (32 bsegs x 16 oblocks — the config with FETCH=24MB) and stages tiles
// with global_load_lds width=16 (contiguous DMA, zero staging VALU).
//
// Packed layout: tile t = batch rows 8t..8t+7. Cell (t,c) = 16 B at
// ws[(t*4096+c)*16]: dword0 = rows(0,1) bf16 lo/hi, dword1 = rows(2,3),
// dword2 = rows(4,5), dword3 = rows(6,7).
// Gather: one ds_read_b128 at idx*16 yields column idx for 8 batch rows.

__device__ __forceinline__ unsigned bf16_rne(float f) {
    unsigned u = __float_as_uint(f);
    return (u + 0x7fffu + ((u >> 16) & 1u)) >> 16;   // round-to-nearest-even bf16
}

// ---------------- Phase 1: pack fp32 -> bf16 cells ----------------
__global__ __launch_bounds__(256) void pack_kernel(
    const float* __restrict__ input, uint4* __restrict__ wsp)
{
    const int idx = blockIdx.x * 256 + threadIdx.x;   // [0, 524288): 2 cells each
    const int t   = idx >> 11;                        // tile [0,256)
    const int c0  = (idx & 2047) << 1;                // column pair [0,4096)

    const float* p = input + (size_t)t * 8 * IN_DIM + c0;
    const float2 r0 = *reinterpret_cast<const float2*>(p + 0 * IN_DIM);
    const float2 r1 = *reinterpret_cast<const float2*>(p + 1 * IN_DIM);
    const float2 r2 = *reinterpret_cast<const float2*>(p + 2 * IN_DIM);
    const float2 r3 = *reinterpret_cast<const float2*>(p + 3 * IN_DIM);
    const float2 r4 = *reinterpret_cast<const float2*>(p + 4 * IN_DIM);
    const float2 r5 = *reinterpret_cast<const float2*>(p + 5 * IN_DIM);
    const float2 r6 = *reinterpret_cast<const float2*>(p + 6 * IN_DIM);
    const float2 r7 = *reinterpret_cast<const float2*>(p + 7 * IN_DIM);

    uint4 a, b;
    a.x = bf16_rne(r0.x) | (bf16_rne(r1.x) << 16);
    a.y = bf16_rne(r2.x) | (bf16_rne(r3.x) << 16);
    a.z = bf16_rne(r4.x) | (bf16_rne(r5.x) << 16);
    a.w = bf16_rne(r6.x) | (bf16_rne(r7.x) << 16);
    b.x = bf16_rne(r0.y) | (bf16_rne(r1.y) << 16);
    b.y = bf16_rne(r2.y) | (bf16_rne(r3.y) << 16);
    b.z = bf16_rne(r4.y) | (bf16_rne(r5.y) << 16);
    b.w = bf16_rne(r6.y) | (bf16_rne(r7.y) << 16);

    uint4* q = wsp + (size_t)t * IN_DIM + c0;
    q[0] = a;
    q[1] = b;
}

// ---------------- Phase 2: gather + accumulate ----------------
__global__ __launch_bounds__(256, 2) void condensed_kernel(
    const uint4* __restrict__ wsp,
    const float* __restrict__ weight,
    const float* __restrict__ bias,
    const int*   __restrict__ mask,
    float*       __restrict__ out)
{
    __shared__ __align__(16) uint4 lds[IN_DIM];       // 64 KB: one 8-row tile

    const int tid  = threadIdx.x;
    const int o    = blockIdx.y * 256 + tid;
    const int bseg = blockIdx.x * 64;                 // 64 batch rows per block

    // ---- idx -> LDS byte addresses + weights, in registers ----
    unsigned addrs[FAN];
    float    wv[FAN];
    {
        const int4*   mv = reinterpret_cast<const int4*>(mask)     + o * (FAN / 4);
        const float4* wp = reinterpret_cast<const float4*>(weight) + o * (FAN / 4);
        #pragma unroll
        for (int j = 0; j < FAN / 4; ++j) {
            int4   m4 = mv[j];
            float4 w4 = wp[j];
            addrs[4*j+0] = (unsigned)m4.x << 4;
            addrs[4*j+1] = (unsigned)m4.y << 4;
            addrs[4*j+2] = (unsigned)m4.z << 4;
            addrs[4*j+3] = (unsigned)m4.w << 4;
            wv[4*j+0] = w4.x;
            wv[4*j+1] = w4.y;
            wv[4*j+2] = w4.z;
            wv[4*j+3] = w4.w;
        }
    }
    const float bv = bias[o];

    for (int bt = 0; bt < 8; ++bt) {                  // 8 tiles x 8 rows = 64 rows
        const int tile = (bseg >> 3) + bt;            // global tile index
        const int b0   = bseg + bt * 8;

        __syncthreads();                              // previous tile's readers done

        // ---- stage 64 KB tile: contiguous DMA, lane-contiguous dst ----
        const uint4* src = wsp + (size_t)tile * IN_DIM + tid;
        #pragma unroll
        for (int it = 0; it < 16; ++it) {
            __builtin_amdgcn_global_load_lds(
                (const __attribute__((address_space(1))) unsigned*)(src + it * 256),
                (__attribute__((address_space(3))) unsigned*)(lds + it * 256 + tid),
                16, 0, 0);
        }

        __syncthreads();                              // drains vmcnt -> LDS valid

        // ---- gather + accumulate: 64 x ds_read_b128, 8 rows each ----
        float acc[8];
        #pragma unroll
        for (int r = 0; r < 8; ++r) acc[r] = 0.0f;

        #pragma unroll
        for (int j = 0; j < FAN; ++j) {
            const uint4 g = *reinterpret_cast<const uint4*>(
                reinterpret_cast<const char*>(lds) + addrs[j]);
            const float wj = wv[j];
            acc[0] = fmaf(__uint_as_float(g.x << 16),          wj, acc[0]);
            acc[1] = fmaf(__uint_as_float(g.x & 0xffff0000u),  wj, acc[1]);
            acc[2] = fmaf(__uint_as_float(g.y << 16),          wj, acc[2]);
            acc[3] = fmaf(__uint_as_float(g.y & 0xffff0000u),  wj, acc[3]);
            acc[4] = fmaf(__uint_as_float(g.z << 16),          wj, acc[4]);
            acc[5] = fmaf(__uint_as_float(g.z & 0xffff0000u),  wj, acc[5]);
            acc[6] = fmaf(__uint_as_float(g.w << 16),          wj, acc[6]);
            acc[7] = fmaf(__uint_as_float(g.w & 0xffff0000u),  wj, acc[7]);
        }

        // ---- write 8 outputs (coalesced across threads) ----
        float* op = out + (size_t)b0 * OUT_DIM + o;
        #pragma unroll
        for (int r = 0; r < 8; ++r) {
            op[(size_t)r * OUT_DIM] = acc[r] + bv;
        }
    }
}

extern "C" void kernel_launch(void* const* d_in, const int* in_sizes, int n_in,
                              void* d_out, int out_size, void* d_ws, size_t ws_size,
                              hipStream_t stream) {
    const float* input  = (const float*)d_in[0];
    const float* weight = (const float*)d_in[1];
    const float* bias   = (const float*)d_in[2];
    const int*   mask   = (const int*)d_in[3];
    float*       out    = (float*)d_out;
    uint4*       wsp    = (uint4*)d_ws;               // needs 16 MiB

    pack_kernel<<<2048, 256, 0, stream>>>(input, wsp);
    dim3 grid(32, 16);   // R1's proven cache-friendly grid: 512 blocks = 2/CU
    condensed_kernel<<<grid, 256, 0, stream>>>(wsp, weight, bias, mask, out);
}